// Round 1
// baseline (1783.235 us; speedup 1.0000x reference)
//
#include <hip/hip_runtime.h>

#define N_NODES 100000
#define N_EDGES 3200000
#define F_IN    1433
#define HID     16
#define N_CLS   7
#define KSPLIT  4
#define KCHUNK  ((F_IN + KSPLIT - 1) / KSPLIT)      // 359
#define ROWBLKS ((N_NODES + 255) / 256)             // 391
#define SCAN_BS 512
#define SCAN_NB ((N_NODES + SCAN_BS - 1) / SCAN_BS) // 196

// ---------------- CSR build ----------------

__global__ void zero_deg_kernel(int* __restrict__ deg) {
    int i = blockIdx.x * blockDim.x + threadIdx.x;
    if (i < N_NODES) deg[i] = 0;
}

__global__ void count_deg_kernel(const int* __restrict__ dst, int* __restrict__ deg) {
    int e = blockIdx.x * blockDim.x + threadIdx.x;
    if (e < N_EDGES) atomicAdd(&deg[dst[e]], 1);
}

__global__ void scan_block_kernel(const int* __restrict__ deg, int* __restrict__ off,
                                  int* __restrict__ bsum) {
    __shared__ int s[SCAN_BS];
    int t = threadIdx.x;
    int g = blockIdx.x * SCAN_BS + t;
    int v = (g < N_NODES) ? deg[g] : 0;
    s[t] = v;
    __syncthreads();
    for (int d = 1; d < SCAN_BS; d <<= 1) {
        int add = (t >= d) ? s[t - d] : 0;
        __syncthreads();
        s[t] += add;
        __syncthreads();
    }
    if (g < N_NODES) off[g] = s[t] - v;          // exclusive within block
    if (t == SCAN_BS - 1) bsum[blockIdx.x] = s[t]; // block total
}

__global__ void scan_sums_kernel(int* __restrict__ bsum) {
    __shared__ int s[256];
    int t = threadIdx.x;
    int v = (t < SCAN_NB) ? bsum[t] : 0;
    s[t] = v;
    __syncthreads();
    for (int d = 1; d < 256; d <<= 1) {
        int add = (t >= d) ? s[t - d] : 0;
        __syncthreads();
        s[t] += add;
        __syncthreads();
    }
    if (t < SCAN_NB) bsum[t] = s[t] - v;         // exclusive over blocks
}

__global__ void add_base_kernel(int* __restrict__ off, const int* __restrict__ bsum,
                                int* __restrict__ cur) {
    int t = threadIdx.x;
    int b = blockIdx.x;
    int g = b * SCAN_BS + t;
    if (g < N_NODES) {
        int o = off[g] + bsum[b];
        off[g] = o;
        cur[g] = o;
    }
}

__global__ void fill_csr_kernel(const int* __restrict__ src, const int* __restrict__ dst,
                                int* __restrict__ cur, int* __restrict__ csr) {
    int e = blockIdx.x * blockDim.x + threadIdx.x;
    if (e < N_EDGES) {
        int p = atomicAdd(&cur[dst[e]], 1);
        csr[p] = src[e];
    }
}

// ---------------- layer 1: t1 = x @ W1 (K-split partials) ----------------

__global__ __launch_bounds__(256) void gemm1_kernel(const float* __restrict__ x,
                                                    const float* __restrict__ W1,
                                                    float* __restrict__ t1p) {
    int rowblk = blockIdx.x % ROWBLKS;
    int slice  = blockIdx.x / ROWBLKS;
    int row = rowblk * 256 + threadIdx.x;
    if (row >= N_NODES) return;
    int k0 = slice * KCHUNK;
    int k1 = k0 + KCHUNK;
    if (k1 > F_IN) k1 = F_IN;
    const float* __restrict__ xr = x + (size_t)row * F_IN;
    float acc[HID];
#pragma unroll
    for (int j = 0; j < HID; ++j) acc[j] = 0.f;
    int k = k0;
    for (; k + 2 <= k1; k += 2) {
        float xv0 = xr[k];
        float xv1 = xr[k + 1];
        const float* w0 = W1 + (size_t)k * HID;   // wave-uniform -> s_load
#pragma unroll
        for (int j = 0; j < HID; ++j) acc[j] = fmaf(xv0, w0[j], acc[j]);
#pragma unroll
        for (int j = 0; j < HID; ++j) acc[j] = fmaf(xv1, w0[HID + j], acc[j]);
    }
    if (k < k1) {
        float xv = xr[k];
        const float* w0 = W1 + (size_t)k * HID;
#pragma unroll
        for (int j = 0; j < HID; ++j) acc[j] = fmaf(xv, w0[j], acc[j]);
    }
    float* o = t1p + (size_t)slice * (N_NODES * HID) + (size_t)row * HID;
#pragma unroll
    for (int j = 0; j < HID; ++j) o[j] = acc[j];
}

__global__ void reduce_t1_kernel(const float* __restrict__ t1p, float* __restrict__ t1) {
    int i = blockIdx.x * blockDim.x + threadIdx.x;
    if (i >= N_NODES * HID) return;
    float a = 0.f;
#pragma unroll
    for (int s = 0; s < KSPLIT; ++s) a += t1p[(size_t)s * (N_NODES * HID) + i];
    t1[i] = a;
}

// h = relu(gather-sum(t1) + t1 + b1); 16 lanes per node
__global__ void agg1_kernel(const float* __restrict__ t1, const int* __restrict__ off,
                            const int* __restrict__ deg, const int* __restrict__ csr,
                            const float* __restrict__ b1, float* __restrict__ h) {
    int tid = blockIdx.x * blockDim.x + threadIdx.x;
    if (tid >= N_NODES * HID) return;
    int node = tid >> 4;
    int f = tid & 15;
    int o = off[node];
    int d = deg[node];
    float a = t1[tid] + b1[f];                   // self-loop + bias
    for (int e = 0; e < d; ++e) {
        int s = csr[o + e];
        a += t1[(s << 4) + f];
    }
    h[tid] = fmaxf(a, 0.f);
}

// ---------------- layer 2 ----------------

__global__ void gemm2_kernel(const float* __restrict__ h, const float* __restrict__ W2,
                             float* __restrict__ t2) {
    int node = blockIdx.x * blockDim.x + threadIdx.x;
    if (node >= N_NODES) return;
    const float4* hr = (const float4*)(h + (size_t)node * HID);
    float hv[HID];
    ((float4*)hv)[0] = hr[0];
    ((float4*)hv)[1] = hr[1];
    ((float4*)hv)[2] = hr[2];
    ((float4*)hv)[3] = hr[3];
#pragma unroll
    for (int c = 0; c < N_CLS; ++c) {
        float a = 0.f;
#pragma unroll
        for (int j = 0; j < HID; ++j) a = fmaf(hv[j], W2[j * N_CLS + c], a);
        t2[node * N_CLS + c] = a;
    }
}

// out = gather-sum(t2) + t2 + b2; 8 lanes per node (7 active)
__global__ void agg2_kernel(const float* __restrict__ t2, const int* __restrict__ off,
                            const int* __restrict__ deg, const int* __restrict__ csr,
                            const float* __restrict__ b2, float* __restrict__ out) {
    int tid = blockIdx.x * blockDim.x + threadIdx.x;
    if (tid >= N_NODES * 8) return;
    int node = tid >> 3;
    int c = tid & 7;
    if (c >= N_CLS) return;
    int o = off[node];
    int d = deg[node];
    float a = t2[node * N_CLS + c] + b2[c];
    for (int e = 0; e < d; ++e) a += t2[csr[o + e] * N_CLS + c];
    out[node * N_CLS + c] = a;
}

// ---------------- launch ----------------

extern "C" void kernel_launch(void* const* d_in, const int* in_sizes, int n_in,
                              void* d_out, int out_size, void* d_ws, size_t ws_size,
                              hipStream_t stream) {
    const float* x  = (const float*)d_in[0];
    const int*   ei = (const int*)d_in[1];
    const float* W1 = (const float*)d_in[2];
    const float* b1 = (const float*)d_in[3];
    const float* W2 = (const float*)d_in[4];
    const float* b2 = (const float*)d_in[5];
    const int* src = ei;
    const int* dst = ei + N_EDGES;
    float* out = (float*)d_out;

    char* w = (char*)d_ws;
    float* t1p = (float*)w;  w += (size_t)KSPLIT * N_NODES * HID * sizeof(float);
    float* t1  = (float*)w;  w += (size_t)N_NODES * HID * sizeof(float);
    int* deg   = (int*)w;    w += (size_t)N_NODES * sizeof(int);
    int* off   = (int*)w;    w += (size_t)N_NODES * sizeof(int);
    int* cur   = (int*)w;    w += (size_t)N_NODES * sizeof(int);
    int* bsum  = (int*)w;    w += 256 * sizeof(int);
    int* csr   = (int*)w;    w += (size_t)N_EDGES * sizeof(int);
    // t1p is dead after reduce_t1; reuse it for h and t2
    float* h  = t1p;
    float* t2 = t1p + (size_t)N_NODES * HID;

    // CSR build
    zero_deg_kernel<<<ROWBLKS, 256, 0, stream>>>(deg);
    count_deg_kernel<<<(N_EDGES + 255) / 256, 256, 0, stream>>>(dst, deg);
    scan_block_kernel<<<SCAN_NB, SCAN_BS, 0, stream>>>(deg, off, bsum);
    scan_sums_kernel<<<1, 256, 0, stream>>>(bsum);
    add_base_kernel<<<SCAN_NB, SCAN_BS, 0, stream>>>(off, bsum, cur);
    fill_csr_kernel<<<(N_EDGES + 255) / 256, 256, 0, stream>>>(src, dst, cur, csr);

    // layer 1
    gemm1_kernel<<<ROWBLKS * KSPLIT, 256, 0, stream>>>(x, W1, t1p);
    reduce_t1_kernel<<<(N_NODES * HID + 255) / 256, 256, 0, stream>>>(t1p, t1);
    agg1_kernel<<<(N_NODES * HID + 255) / 256, 256, 0, stream>>>(t1, off, deg, csr, b1, h);

    // layer 2
    gemm2_kernel<<<ROWBLKS, 256, 0, stream>>>(h, W2, t2);
    agg2_kernel<<<(N_NODES * 8 + 255) / 256, 256, 0, stream>>>(t2, off, deg, csr, b2, out);
}

// Round 2
// 773.256 us; speedup vs baseline: 2.3061x; 2.3061x over previous
//
#include <hip/hip_runtime.h>

#define N_NODES 100000
#define N_EDGES 3200000
#define F_IN    1433
#define HID     16
#define N_CLS   7
#define KSPLIT  4
#define KCHUNK  ((F_IN + KSPLIT - 1) / KSPLIT)      // 359
#define ROWBLKS ((N_NODES + 255) / 256)             // 391
#define SCAN_BS 512
#define SCAN_NB ((N_NODES + SCAN_BS - 1) / SCAN_BS) // 196

// ---------------- CSR build ----------------

__global__ void zero_deg_kernel(int* __restrict__ deg) {
    int i = blockIdx.x * blockDim.x + threadIdx.x;
    if (i < N_NODES) deg[i] = 0;
}

__global__ void count_deg_kernel(const int* __restrict__ dst, int* __restrict__ deg) {
    int e = blockIdx.x * blockDim.x + threadIdx.x;
    if (e < N_EDGES) atomicAdd(&deg[dst[e]], 1);
}

__global__ void scan_block_kernel(const int* __restrict__ deg, int* __restrict__ off,
                                  int* __restrict__ bsum) {
    __shared__ int s[SCAN_BS];
    int t = threadIdx.x;
    int g = blockIdx.x * SCAN_BS + t;
    int v = (g < N_NODES) ? deg[g] : 0;
    s[t] = v;
    __syncthreads();
    for (int d = 1; d < SCAN_BS; d <<= 1) {
        int add = (t >= d) ? s[t - d] : 0;
        __syncthreads();
        s[t] += add;
        __syncthreads();
    }
    if (g < N_NODES) off[g] = s[t] - v;          // exclusive within block
    if (t == SCAN_BS - 1) bsum[blockIdx.x] = s[t]; // block total
}

__global__ void scan_sums_kernel(int* __restrict__ bsum) {
    __shared__ int s[256];
    int t = threadIdx.x;
    int v = (t < SCAN_NB) ? bsum[t] : 0;
    s[t] = v;
    __syncthreads();
    for (int d = 1; d < 256; d <<= 1) {
        int add = (t >= d) ? s[t - d] : 0;
        __syncthreads();
        s[t] += add;
        __syncthreads();
    }
    if (t < SCAN_NB) bsum[t] = s[t] - v;         // exclusive over blocks
}

__global__ void add_base_kernel(int* __restrict__ off, const int* __restrict__ bsum,
                                int* __restrict__ cur) {
    int t = threadIdx.x;
    int b = blockIdx.x;
    int g = b * SCAN_BS + t;
    if (g < N_NODES) {
        int o = off[g] + bsum[b];
        off[g] = o;
        cur[g] = o;
    }
}

__global__ void fill_csr_kernel(const int* __restrict__ src, const int* __restrict__ dst,
                                int* __restrict__ cur, int* __restrict__ csr) {
    int e = blockIdx.x * blockDim.x + threadIdx.x;
    if (e < N_EDGES) {
        int p = atomicAdd(&cur[dst[e]], 1);
        csr[p] = src[e];
    }
}

// ---------------- layer 1: t1 = x @ W1 (K-split partials) ----------------
// Thread-per-row, k wave-uniform (W1 -> s_loads). Key: 16 x-loads issued
// back-to-back per iteration so each lane's 64B line is consumed within one
// instruction burst (MSHR/L1 merge) -> HBM fetch ~= 573 MB exactly.

__global__ __launch_bounds__(256) void gemm1_kernel(const float* __restrict__ x,
                                                    const float* __restrict__ W1,
                                                    float* __restrict__ t1p) {
    int rowblk = blockIdx.x % ROWBLKS;
    int slice  = blockIdx.x / ROWBLKS;
    int row = rowblk * 256 + threadIdx.x;
    if (row >= N_NODES) return;
    int k0 = slice * KCHUNK;
    int k1 = k0 + KCHUNK;
    if (k1 > F_IN) k1 = F_IN;
    const float* __restrict__ xr = x + (size_t)row * F_IN;
    float acc[HID];
#pragma unroll
    for (int j = 0; j < HID; ++j) acc[j] = 0.f;
    int k = k0;
    for (; k + 16 <= k1; k += 16) {
        float xv[16];
#pragma unroll
        for (int i = 0; i < 16; ++i) xv[i] = xr[k + i];   // 16 adjacent dword loads
#pragma unroll
        for (int i = 0; i < 16; ++i) {
            const float* w = W1 + (size_t)(k + i) * HID;  // wave-uniform -> s_load
#pragma unroll
            for (int j = 0; j < HID; ++j) acc[j] = fmaf(xv[i], w[j], acc[j]);
        }
    }
    for (; k < k1; ++k) {                                 // tail (<=15, uniform)
        float xv = xr[k];
        const float* w = W1 + (size_t)k * HID;
#pragma unroll
        for (int j = 0; j < HID; ++j) acc[j] = fmaf(xv, w[j], acc[j]);
    }
    float* o = t1p + (size_t)slice * (N_NODES * HID) + (size_t)row * HID;
#pragma unroll
    for (int j = 0; j < HID; ++j) o[j] = acc[j];
}

__global__ void reduce_t1_kernel(const float* __restrict__ t1p, float* __restrict__ t1) {
    int i = blockIdx.x * blockDim.x + threadIdx.x;
    if (i >= N_NODES * HID) return;
    float a = 0.f;
#pragma unroll
    for (int s = 0; s < KSPLIT; ++s) a += t1p[(size_t)s * (N_NODES * HID) + i];
    t1[i] = a;
}

// h = relu(gather-sum(t1) + t1 + b1); 16 lanes per node
__global__ void agg1_kernel(const float* __restrict__ t1, const int* __restrict__ off,
                            const int* __restrict__ deg, const int* __restrict__ csr,
                            const float* __restrict__ b1, float* __restrict__ h) {
    int tid = blockIdx.x * blockDim.x + threadIdx.x;
    if (tid >= N_NODES * HID) return;
    int node = tid >> 4;
    int f = tid & 15;
    int o = off[node];
    int d = deg[node];
    float a = t1[tid] + b1[f];                   // self-loop + bias
    for (int e = 0; e < d; ++e) {
        int s = csr[o + e];
        a += t1[(s << 4) + f];
    }
    h[tid] = fmaxf(a, 0.f);
}

// ---------------- layer 2 ----------------

__global__ void gemm2_kernel(const float* __restrict__ h, const float* __restrict__ W2,
                             float* __restrict__ t2) {
    int node = blockIdx.x * blockDim.x + threadIdx.x;
    if (node >= N_NODES) return;
    const float4* hr = (const float4*)(h + (size_t)node * HID);
    float hv[HID];
    ((float4*)hv)[0] = hr[0];
    ((float4*)hv)[1] = hr[1];
    ((float4*)hv)[2] = hr[2];
    ((float4*)hv)[3] = hr[3];
#pragma unroll
    for (int c = 0; c < N_CLS; ++c) {
        float a = 0.f;
#pragma unroll
        for (int j = 0; j < HID; ++j) a = fmaf(hv[j], W2[j * N_CLS + c], a);
        t2[node * N_CLS + c] = a;
    }
}

// out = gather-sum(t2) + t2 + b2; 8 lanes per node (7 active)
__global__ void agg2_kernel(const float* __restrict__ t2, const int* __restrict__ off,
                            const int* __restrict__ deg, const int* __restrict__ csr,
                            const float* __restrict__ b2, float* __restrict__ out) {
    int tid = blockIdx.x * blockDim.x + threadIdx.x;
    if (tid >= N_NODES * 8) return;
    int node = tid >> 3;
    int c = tid & 7;
    if (c >= N_CLS) return;
    int o = off[node];
    int d = deg[node];
    float a = t2[node * N_CLS + c] + b2[c];
    for (int e = 0; e < d; ++e) a += t2[csr[o + e] * N_CLS + c];
    out[node * N_CLS + c] = a;
}

// ---------------- launch ----------------

extern "C" void kernel_launch(void* const* d_in, const int* in_sizes, int n_in,
                              void* d_out, int out_size, void* d_ws, size_t ws_size,
                              hipStream_t stream) {
    const float* x  = (const float*)d_in[0];
    const int*   ei = (const int*)d_in[1];
    const float* W1 = (const float*)d_in[2];
    const float* b1 = (const float*)d_in[3];
    const float* W2 = (const float*)d_in[4];
    const float* b2 = (const float*)d_in[5];
    const int* src = ei;
    const int* dst = ei + N_EDGES;
    float* out = (float*)d_out;

    char* w = (char*)d_ws;
    float* t1p = (float*)w;  w += (size_t)KSPLIT * N_NODES * HID * sizeof(float);
    float* t1  = (float*)w;  w += (size_t)N_NODES * HID * sizeof(float);
    int* deg   = (int*)w;    w += (size_t)N_NODES * sizeof(int);
    int* off   = (int*)w;    w += (size_t)N_NODES * sizeof(int);
    int* cur   = (int*)w;    w += (size_t)N_NODES * sizeof(int);
    int* bsum  = (int*)w;    w += 256 * sizeof(int);
    int* csr   = (int*)w;    w += (size_t)N_EDGES * sizeof(int);
    // t1p is dead after reduce_t1; reuse it for h and t2
    float* h  = t1p;
    float* t2 = t1p + (size_t)N_NODES * HID;

    // CSR build
    zero_deg_kernel<<<ROWBLKS, 256, 0, stream>>>(deg);
    count_deg_kernel<<<(N_EDGES + 255) / 256, 256, 0, stream>>>(dst, deg);
    scan_block_kernel<<<SCAN_NB, SCAN_BS, 0, stream>>>(deg, off, bsum);
    scan_sums_kernel<<<1, 256, 0, stream>>>(bsum);
    add_base_kernel<<<SCAN_NB, SCAN_BS, 0, stream>>>(off, bsum, cur);
    fill_csr_kernel<<<(N_EDGES + 255) / 256, 256, 0, stream>>>(src, dst, cur, csr);

    // layer 1
    gemm1_kernel<<<ROWBLKS * KSPLIT, 256, 0, stream>>>(x, W1, t1p);
    reduce_t1_kernel<<<(N_NODES * HID + 255) / 256, 256, 0, stream>>>(t1p, t1);
    agg1_kernel<<<(N_NODES * HID + 255) / 256, 256, 0, stream>>>(t1, off, deg, csr, b1, h);

    // layer 2
    gemm2_kernel<<<ROWBLKS, 256, 0, stream>>>(h, W2, t2);
    agg2_kernel<<<(N_NODES * 8 + 255) / 256, 256, 0, stream>>>(t2, off, deg, csr, b2, out);
}